// Round 2
// baseline (3687.037 us; speedup 1.0000x reference)
//
#include <hip/hip_runtime.h>
#include <hip/hip_bf16.h>

#define N_OUT 14592
#define HVIS 1024
#define IC 4096
#define PH 4096
#define TH 2048
#define NTILES 30
#define LN_EPS 1e-5f

typedef float f32x4 __attribute__((ext_vector_type(4)));
typedef __bf16 bf16x8 __attribute__((ext_vector_type(8)));
typedef unsigned short us8 __attribute__((ext_vector_type(8)));
typedef unsigned short us4 __attribute__((ext_vector_type(4)));

__device__ inline unsigned short f2bf(float x) {
    union { float f; unsigned u; } v; v.f = x;
    unsigned r = v.u + 0x7FFFu + ((v.u >> 16) & 1u);   // RNE
    return (unsigned short)(r >> 16);
}
__device__ inline float bf2f(unsigned short h) {
    union { unsigned u; float f; } v; v.u = ((unsigned)h) << 16; return v.f;
}

// ---------------- kernel: build gather index ----------------
__global__ void build_index(const int* __restrict__ ss_raw, int* __restrict__ idx) {
    __shared__ int t_w[NTILES], t_in[NTILES], t_out[NTILES + 1];
    if (threadIdx.x == 0) {
        int stride = (ss_raw[1] == 0) ? 2 : 1;   // int64 vs int32 spatial_shapes
        int in_off = 0, out_off = 0;
        for (int t = 0; t < NTILES; ++t) {
            int h = ss_raw[(2 * t + 0) * stride];
            int w = ss_raw[(2 * t + 1) * stride];
            t_w[t] = w; t_in[t] = in_off; t_out[t] = out_off;
            in_off += h * w;
            out_off += (h / 2) * (w / 2);
        }
        t_out[NTILES] = out_off;
    }
    __syncthreads();
    for (int r = blockIdx.x * blockDim.x + threadIdx.x; r < N_OUT;
         r += gridDim.x * blockDim.x) {
        int t = 0;
        while (t + 1 < NTILES && r >= t_out[t + 1]) ++t;
        int local = r - t_out[t];
        int w = t_w[t];
        int wb = w >> 1;
        int i0 = local / wb;
        int i2 = local - i0 * wb;
        int base = t_in[t] + (2 * i0) * w + 2 * i2;
        idx[4 * r + 0] = base;
        idx[4 * r + 1] = base + 1;
        idx[4 * r + 2] = base + w;
        idx[4 * r + 3] = base + w + 1;
    }
}

// ---------------- kernel: per-row LN stats ----------------
__global__ void row_stats(const float* __restrict__ vis, const int* __restrict__ idx,
                          float* __restrict__ mu, float* __restrict__ rsig) {
    const int r = blockIdx.x;
    const int tid = threadIdx.x;
    int toks[4];
#pragma unroll
    for (int j = 0; j < 4; ++j) toks[j] = idx[4 * r + j];
    float s = 0.f, ss = 0.f;
#pragma unroll
    for (int i = 0; i < 4; ++i) {
        int slot = tid + i * 256;
        int j = slot >> 8;
        int c4 = slot & 255;
        const f32x4 v = *(const f32x4*)(vis + (size_t)toks[j] * HVIS + c4 * 4);
        s += v[0] + v[1] + v[2] + v[3];
        ss += v[0] * v[0] + v[1] * v[1] + v[2] * v[2] + v[3] * v[3];
    }
#pragma unroll
    for (int off = 32; off > 0; off >>= 1) {
        s += __shfl_down(s, off);
        ss += __shfl_down(ss, off);
    }
    __shared__ float ps[4], pss[4];
    int w = tid >> 6;
    if ((tid & 63) == 0) { ps[w] = s; pss[w] = ss; }
    __syncthreads();
    if (tid == 0) {
        float S = ps[0] + ps[1] + ps[2] + ps[3];
        float SS = pss[0] + pss[1] + pss[2] + pss[3];
        float m = S * (1.f / (float)IC);
        float v = SS * (1.f / (float)IC) - m * m;
        mu[r] = m;
        rsig[r] = rsqrtf(v + LN_EPS);
    }
}

// ---------------- kernel: b1' = b1 + beta @ w1 ----------------
__global__ void bias_fold(const float* __restrict__ b1, const float* __restrict__ beta,
                          const float* __restrict__ w1, float* __restrict__ b1p) {
    __shared__ float part[8][32];
    const int n0 = blockIdx.x * 32;
    const int c = threadIdx.x & 31, ph = threadIdx.x >> 5;
    float acc = 0.f;
    for (int k = ph; k < IC; k += 8)
        acc += beta[k] * w1[(size_t)k * PH + n0 + c];
    part[ph][c] = acc;
    __syncthreads();
    if (threadIdx.x < 32) {
        float s = b1[n0 + c];
#pragma unroll
        for (int i = 0; i < 8; ++i) s += part[i][c];
        b1p[n0 + c] = s;
    }
}

// ---------------- kernel: transpose + split weights into bf16 hi/lo ----------------
// src: K x N fp32 row-major  ->  dhi/dlo: N x K bf16 row-major (optionally row-scaled by gamma[k])
template <int APPLY_GAMMA>
__global__ void transpose_split(const float* __restrict__ src, const float* __restrict__ gamma,
                                unsigned short* __restrict__ dhi, unsigned short* __restrict__ dlo,
                                int K, int N) {
    __shared__ float t[32][33];
    const int k0 = blockIdx.y * 32, n0 = blockIdx.x * 32;
    const int tid = threadIdx.x;
    {
        const int r = tid >> 3, c4 = (tid & 7) * 4;
        f32x4 v = *(const f32x4*)(src + (size_t)(k0 + r) * N + n0 + c4);
        if (APPLY_GAMMA) { const float g = gamma[k0 + r]; v = v * g; }
        t[r][c4 + 0] = v[0]; t[r][c4 + 1] = v[1]; t[r][c4 + 2] = v[2]; t[r][c4 + 3] = v[3];
    }
    __syncthreads();
    const int nr = tid >> 3, kc = (tid & 7) * 4;
    us4 h, l;
#pragma unroll
    for (int i = 0; i < 4; ++i) {
        const float x = t[kc + i][nr];
        const unsigned short hb = f2bf(x);
        h[i] = hb; l[i] = f2bf(x - bf2f(hb));
    }
    *(us4*)(dhi + (size_t)(n0 + nr) * K + k0 + kc) = h;
    *(us4*)(dlo + (size_t)(n0 + nr) * K + k0 + kc) = l;
}

// ---------------- split-bf16 MFMA GEMM ----------------
// C[M,N] = A @ B(+bias), K = 4096, emulating fp32 via hi/lo bf16 (3 MFMA products).
// MODE 0: A = LN-normalized gather of vis (per-row mu/rsig; gamma folded into B,
//         beta folded into bias); epilogue = bias + exact GELU -> split bf16 store.
// MODE 1: A = (Ahi,Alo) bf16 pair; epilogue = bias -> fp32 store.
// B given transposed as (Bhi,Blo): N x K bf16.
// LDS tile layout per matrix: [frag(8)][kchunk(4)][row16][8 bf16] -> frag reads stride-1.
template <int MODE>
__global__ __launch_bounds__(256, 2) void gemm_split(
    const float* __restrict__ vis, const int* __restrict__ idx,
    const float* __restrict__ mu, const float* __restrict__ rsig,
    const unsigned short* __restrict__ Ahi, const unsigned short* __restrict__ Alo,
    const unsigned short* __restrict__ Bhi, const unsigned short* __restrict__ Blo,
    const float* __restrict__ bias,
    unsigned short* __restrict__ outHi, unsigned short* __restrict__ outLo,
    float* __restrict__ outF, int Ncols) {
    __shared__ unsigned short lds[2][4][4096];   // [buf][Ahi,Alo,Bhi,Blo] = 64 KiB

    const int tid = threadIdx.x;
    const int lane = tid & 63;
    const int wv = tid >> 6;
    const int wr = wv >> 1, wc = wv & 1;

    // bijective XCD-chunked swizzle (grid size divisible by 8), bn-major so each
    // XCD walks contiguous bm for a fixed bn -> B-panel (4MB) stays in its L2.
    const int nbx = gridDim.x;
    const int d = blockIdx.y * nbx + blockIdx.x;
    const int q = (nbx * 114) >> 3;
    const int swz = (d & 7) * q + (d >> 3);
    const int bn = swz / 114;
    const int bm = swz - bn * 114;

    const int sr = tid >> 1;   // staged row (A) / col (B), 0..127
    const int sh = tid & 1;    // k-half of the 32-wide tile

    float s_mu = 0.f, s_rs = 0.f;
    if constexpr (MODE == 0) {
        s_mu = mu[bm * 128 + sr];
        s_rs = rsig[bm * 128 + sr];
    }

    const size_t KEL = 4096;
    f32x4 ra0, ra1, ra2, ra3;   // in-flight A (16 fp32 | 2x16B hi + 2x16B lo)
    f32x4 rb0, rb1, rb2, rb3;   // in-flight B (hi 32B, lo 32B)

    auto LOAD = [&](int kt) {
        const int k0 = kt * 32;
        if constexpr (MODE == 0) {
            const int j = k0 >> 10;
            const int tok = idx[4 * (bm * 128 + sr) + j];
            const float* p = vis + (size_t)tok * HVIS + (k0 & 1023) + sh * 16;
            ra0 = *(const f32x4*)(p + 0);  ra1 = *(const f32x4*)(p + 4);
            ra2 = *(const f32x4*)(p + 8);  ra3 = *(const f32x4*)(p + 12);
        } else {
            const unsigned short* pa = Ahi + (size_t)(bm * 128 + sr) * KEL + k0 + sh * 16;
            const unsigned short* pl = Alo + (size_t)(bm * 128 + sr) * KEL + k0 + sh * 16;
            ra0 = *(const f32x4*)(pa); ra1 = *(const f32x4*)(pa + 8);
            ra2 = *(const f32x4*)(pl); ra3 = *(const f32x4*)(pl + 8);
        }
        const unsigned short* pb = Bhi + (size_t)(bn * 128 + sr) * KEL + k0 + sh * 16;
        const unsigned short* pq = Blo + (size_t)(bn * 128 + sr) * KEL + k0 + sh * 16;
        rb0 = *(const f32x4*)(pb); rb1 = *(const f32x4*)(pb + 8);
        rb2 = *(const f32x4*)(pq); rb3 = *(const f32x4*)(pq + 8);
    };

    const int dbase = (sr >> 4) * 512 + (sr & 15) * 8;   // ushort units; + c*128
    const int c0 = 2 * sh, c1 = 2 * sh + 1;

    auto STORE = [&](int buf) {
        if constexpr (MODE == 0) {
            float v[16];
            *(f32x4*)&v[0] = ra0; *(f32x4*)&v[4] = ra1;
            *(f32x4*)&v[8] = ra2; *(f32x4*)&v[12] = ra3;
            us8 h0, h1, l0, l1;
#pragma unroll
            for (int i = 0; i < 8; ++i) {
                const float x = (v[i] - s_mu) * s_rs;
                const unsigned short hb = f2bf(x);
                h0[i] = hb; l0[i] = f2bf(x - bf2f(hb));
                const float y = (v[8 + i] - s_mu) * s_rs;
                const unsigned short hb2 = f2bf(y);
                h1[i] = hb2; l1[i] = f2bf(y - bf2f(hb2));
            }
            *(us8*)&lds[buf][0][dbase + c0 * 128] = h0;
            *(us8*)&lds[buf][0][dbase + c1 * 128] = h1;
            *(us8*)&lds[buf][1][dbase + c0 * 128] = l0;
            *(us8*)&lds[buf][1][dbase + c1 * 128] = l1;
        } else {
            *(f32x4*)&lds[buf][0][dbase + c0 * 128] = ra0;
            *(f32x4*)&lds[buf][0][dbase + c1 * 128] = ra1;
            *(f32x4*)&lds[buf][1][dbase + c0 * 128] = ra2;
            *(f32x4*)&lds[buf][1][dbase + c1 * 128] = ra3;
        }
        *(f32x4*)&lds[buf][2][dbase + c0 * 128] = rb0;
        *(f32x4*)&lds[buf][2][dbase + c1 * 128] = rb1;
        *(f32x4*)&lds[buf][3][dbase + c0 * 128] = rb2;
        *(f32x4*)&lds[buf][3][dbase + c1 * 128] = rb3;
    };

    f32x4 acc[4][4];
#pragma unroll
    for (int i = 0; i < 4; ++i)
#pragma unroll
        for (int j = 0; j < 4; ++j) acc[i][j] = (f32x4)0.f;

    const int foff = (lane >> 4) * 128 + (lane & 15) * 8;

    LOAD(0);
    STORE(0);
    __syncthreads();

    const int NT = 128;   // K/32
    for (int kt = 0; kt < NT; ++kt) {
        const int cur = kt & 1;
        if (kt + 1 < NT) LOAD(kt + 1);

        bf16x8 bh[4], bl[4];
#pragma unroll
        for (int ni = 0; ni < 4; ++ni) {
            bh[ni] = *(const bf16x8*)&lds[cur][2][(wc * 4 + ni) * 512 + foff];
            bl[ni] = *(const bf16x8*)&lds[cur][3][(wc * 4 + ni) * 512 + foff];
        }
#pragma unroll
        for (int mi = 0; mi < 4; ++mi) {
            const bf16x8 ah = *(const bf16x8*)&lds[cur][0][(wr * 4 + mi) * 512 + foff];
            const bf16x8 al = *(const bf16x8*)&lds[cur][1][(wr * 4 + mi) * 512 + foff];
#pragma unroll
            for (int ni = 0; ni < 4; ++ni) {
                acc[mi][ni] = __builtin_amdgcn_mfma_f32_16x16x32_bf16(ah, bh[ni], acc[mi][ni], 0, 0, 0);
                acc[mi][ni] = __builtin_amdgcn_mfma_f32_16x16x32_bf16(ah, bl[ni], acc[mi][ni], 0, 0, 0);
                acc[mi][ni] = __builtin_amdgcn_mfma_f32_16x16x32_bf16(al, bh[ni], acc[mi][ni], 0, 0, 0);
            }
        }
        if (kt + 1 < NT) STORE(cur ^ 1);
        __syncthreads();
    }

    // epilogue: C/D layout col = lane&15, row = (lane>>4)*4 + reg  [HW-verified]
    const int er = bm * 128 + wr * 64 + (lane >> 4) * 4;
    const int ec = bn * 128 + wc * 64 + (lane & 15);
    const float inv_sqrt2 = 0.70710678118654752f;
#pragma unroll
    for (int ni = 0; ni < 4; ++ni) {
        const int c = ec + ni * 16;
        const float bia = bias[c];
#pragma unroll
        for (int mi = 0; mi < 4; ++mi) {
#pragma unroll
            for (int j = 0; j < 4; ++j) {
                const int r = er + mi * 16 + j;
                const float o = acc[mi][ni][j] + bia;
                if constexpr (MODE == 0) {
                    const float g = 0.5f * o * (1.f + erff(o * inv_sqrt2));
                    const unsigned short hb = f2bf(g);
                    outHi[(size_t)r * PH + c] = hb;
                    outLo[(size_t)r * PH + c] = f2bf(g - bf2f(hb));
                } else {
                    outF[(size_t)r * Ncols + c] = o;
                }
            }
        }
    }
}

extern "C" void kernel_launch(void* const* d_in, const int* in_sizes, int n_in,
                              void* d_out, int out_size, void* d_ws, size_t ws_size,
                              hipStream_t stream) {
    const float* vis   = (const float*)d_in[0];
    const int*   ss    = (const int*)d_in[1];
    const float* gamma = (const float*)d_in[2];
    const float* beta  = (const float*)d_in[3];
    const float* w1    = (const float*)d_in[4];
    const float* b1    = (const float*)d_in[5];
    const float* w2    = (const float*)d_in[6];
    const float* b2    = (const float*)d_in[7];
    float* out = (float*)d_out;

    char* ws = (char*)d_ws;
    const size_t MiB = 1024 * 1024;
    int*            idx   = (int*)ws;                       // 228 KiB
    float*          mu    = (float*)(ws + 256 * 1024);      // 57 KiB
    float*          rsig  = (float*)(ws + 320 * 1024);      // 57 KiB
    float*          b1p   = (float*)(ws + 384 * 1024);      // 16 KiB
    unsigned short* w1hi  = (unsigned short*)(ws + 1 * MiB);    // 32 MiB
    unsigned short* w1lo  = (unsigned short*)(ws + 33 * MiB);   // 32 MiB
    unsigned short* w2hi  = (unsigned short*)(ws + 65 * MiB);   // 16 MiB
    unsigned short* w2lo  = (unsigned short*)(ws + 81 * MiB);   // 16 MiB
    unsigned short* Hhi   = (unsigned short*)(ws + 97 * MiB);   // 114 MiB
    unsigned short* Hlo   = (unsigned short*)(ws + 212 * MiB);  // 114 MiB -> end 326 MiB

    build_index<<<57, 256, 0, stream>>>(ss, idx);
    row_stats<<<N_OUT, 256, 0, stream>>>(vis, idx, mu, rsig);
    bias_fold<<<PH / 32, 256, 0, stream>>>(b1, beta, w1, b1p);
    transpose_split<1><<<dim3(PH / 32, IC / 32), 256, 0, stream>>>(w1, gamma, w1hi, w1lo, IC, PH);
    transpose_split<0><<<dim3(TH / 32, PH / 32), 256, 0, stream>>>(w2, nullptr, w2hi, w2lo, PH, TH);

    // GEMM1: H = gelu(LN(gather(vis)) @ (gamma.w1) + b1')  -> split bf16
    gemm_split<0><<<dim3(PH / 128, N_OUT / 128), 256, 0, stream>>>(
        vis, idx, mu, rsig, nullptr, nullptr, w1hi, w1lo, b1p, Hhi, Hlo, nullptr, PH);
    // GEMM2: out = H @ w2 + b2  -> fp32
    gemm_split<1><<<dim3(TH / 128, N_OUT / 128), 256, 0, stream>>>(
        nullptr, nullptr, nullptr, nullptr, Hhi, Hlo, w2hi, w2lo, b2, nullptr, nullptr, out, TH);
}